// Round 1
// baseline (69.634 us; speedup 1.0000x reference)
//
#include <hip/hip_runtime.h>

// ROI-Align (bilinear, half-pixel) — B=1, H=W=128, C=512, POOL=7, N ROIs.
// Output layout: (N, 1, 7, 7, C) flat = ((roi*49 + py*7 + px) * C + c).
// One 128-thread block per output bin; thread t handles channels [4t, 4t+4).

#define POOLN 7
#define FM_H 128
#define FM_W 128
#define FM_C 512

__global__ __launch_bounds__(128) void roi_align_kernel(
    const float* __restrict__ fm,
    const int* __restrict__ rois,
    float* __restrict__ out)
{
    const int p   = blockIdx.x;          // roi*49 + py*7 + px
    const int roi = p / 49;
    const int rem = p - roi * 49;
    const int py  = rem / 7;
    const int px  = rem - py * 7;

    const int4 r = reinterpret_cast<const int4*>(rois)[roi];
    const int x1 = r.x, y1 = r.y, x2 = r.z, y2 = r.w;

    // y coordinate (half-pixel, clipped to [0, size-1], then + start)
    const float sizy = (float)(y2 - y1);
    float cy = ((float)py + 0.5f) * (sizy / (float)POOLN) - 0.5f;
    cy = fminf(fmaxf(cy, 0.0f), sizy - 1.0f);
    const float ys = cy + (float)y1;
    const int   y0 = (int)floorf(ys);
    const int   yb = min(y0 + 1, y2 - 1);
    const float wy = ys - (float)y0;

    // x coordinate
    const float sizx = (float)(x2 - x1);
    float cx = ((float)px + 0.5f) * (sizx / (float)POOLN) - 0.5f;
    cx = fminf(fmaxf(cx, 0.0f), sizx - 1.0f);
    const float xs = cx + (float)x1;
    const int   x0 = (int)floorf(xs);
    const int   xb = min(x0 + 1, x2 - 1);
    const float wx = xs - (float)x0;

    const float4* tl = reinterpret_cast<const float4*>(fm + (size_t)(y0 * FM_W + x0) * FM_C);
    const float4* tr = reinterpret_cast<const float4*>(fm + (size_t)(y0 * FM_W + xb) * FM_C);
    const float4* bl = reinterpret_cast<const float4*>(fm + (size_t)(yb * FM_W + x0) * FM_C);
    const float4* br = reinterpret_cast<const float4*>(fm + (size_t)(yb * FM_W + xb) * FM_C);
    float4*       o  = reinterpret_cast<float4*>(out + (size_t)p * FM_C);

    const int c = threadIdx.x;           // 0..127 — float4 channel index
    const float4 a = tl[c];
    const float4 b = tr[c];
    const float4 d = bl[c];
    const float4 e = br[c];

    float4 res;
    {
        const float top = a.x + (b.x - a.x) * wx;
        const float bot = d.x + (e.x - d.x) * wx;
        res.x = top + (bot - top) * wy;
    }
    {
        const float top = a.y + (b.y - a.y) * wx;
        const float bot = d.y + (e.y - d.y) * wx;
        res.y = top + (bot - top) * wy;
    }
    {
        const float top = a.z + (b.z - a.z) * wx;
        const float bot = d.z + (e.z - d.z) * wx;
        res.z = top + (bot - top) * wy;
    }
    {
        const float top = a.w + (b.w - a.w) * wx;
        const float bot = d.w + (e.w - d.w) * wx;
        res.w = top + (bot - top) * wy;
    }
    o[c] = res;
}

extern "C" void kernel_launch(void* const* d_in, const int* in_sizes, int n_in,
                              void* d_out, int out_size, void* d_ws, size_t ws_size,
                              hipStream_t stream) {
    const float* fm   = (const float*)d_in[0];
    const int*   rois = (const int*)d_in[1];
    float*       out  = (float*)d_out;

    const int N = in_sizes[1] / 4;       // 1024 ROIs
    dim3 grid(N * POOLN * POOLN);        // one block per output bin
    roi_align_kernel<<<grid, 128, 0, stream>>>(fm, rois, out);
}

// Round 4
// 30.663 us; speedup vs baseline: 2.2709x; 2.2709x over previous
//
#include <hip/hip_runtime.h>

// ROI-Align (bilinear, half-pixel) — B=1, H=W=128, C=512, POOL=7, N ROIs.
// Output layout: (N, 1, 7, 7, C) flat = ((roi*49 + py*7 + px) * C + c).
//
// Round-4 (= round-3 resubmit after infra failure): channel-partitioned
// across XCDs.
//   chunk = blockIdx.x & 7  → lands on XCD (blockIdx.x % 8) under the default
//   round-robin dispatch, so each XCD streams only its own 128x128x64 fp32
//   sub-map (exactly 4 MiB = one XCD's L2). Writes are non-temporal so the
//   streaming output doesn't evict the resident sub-map.
// Block = 256 threads = 16 bins x 16 lanes; lane = one float4 of the chunk.

#define POOLN 7
#define FM_H 128
#define FM_W 128
#define FM_C 512
#define NXCD 8
#define CHUNK_C (FM_C / NXCD)        // 64 channels per chunk
#define BINS_PER_BLOCK 16

typedef float f32x4 __attribute__((ext_vector_type(4)));

__global__ __launch_bounds__(256) void roi_align_kernel(
    const float* __restrict__ fm,
    const int* __restrict__ rois,
    float* __restrict__ out,
    int n_bins)
{
    const int chunk  = blockIdx.x & (NXCD - 1);   // → XCD id (heuristic)
    const int group  = blockIdx.x >> 3;
    const int lane_c = threadIdx.x & 15;          // float4 index within chunk
    const int bin    = group * BINS_PER_BLOCK + (threadIdx.x >> 4);
    if (bin >= n_bins) return;

    const int roi = bin / 49;
    const int rem = bin - roi * 49;
    const int py  = rem / 7;
    const int px  = rem - py * 7;

    const int4 r = reinterpret_cast<const int4*>(rois)[roi];
    const int x1 = r.x, y1 = r.y, x2 = r.z, y2 = r.w;

    // y coordinate (half-pixel, clipped to [0, size-1], then + start)
    const float sizy = (float)(y2 - y1);
    float cy = ((float)py + 0.5f) * (sizy / (float)POOLN) - 0.5f;
    cy = fminf(fmaxf(cy, 0.0f), sizy - 1.0f);
    const float ys = cy + (float)y1;
    const int   y0 = (int)floorf(ys);
    const int   yb = min(y0 + 1, y2 - 1);
    const float wy = ys - (float)y0;

    // x coordinate
    const float sizx = (float)(x2 - x1);
    float cx = ((float)px + 0.5f) * (sizx / (float)POOLN) - 0.5f;
    cx = fminf(fmaxf(cx, 0.0f), sizx - 1.0f);
    const float xs = cx + (float)x1;
    const int   x0 = (int)floorf(xs);
    const int   xb = min(x0 + 1, x2 - 1);
    const float wx = xs - (float)x0;

    const int coff = chunk * CHUNK_C + lane_c * 4;

    const f32x4 a = *reinterpret_cast<const f32x4*>(fm + (size_t)(y0 * FM_W + x0) * FM_C + coff);
    const f32x4 b = *reinterpret_cast<const f32x4*>(fm + (size_t)(y0 * FM_W + xb) * FM_C + coff);
    const f32x4 d = *reinterpret_cast<const f32x4*>(fm + (size_t)(yb * FM_W + x0) * FM_C + coff);
    const f32x4 e = *reinterpret_cast<const f32x4*>(fm + (size_t)(yb * FM_W + xb) * FM_C + coff);

    const f32x4 top = a + (b - a) * wx;
    const f32x4 bot = d + (e - d) * wx;
    const f32x4 res = top + (bot - top) * wy;

    f32x4* o = reinterpret_cast<f32x4*>(out + (size_t)bin * FM_C + coff);
    __builtin_nontemporal_store(res, o);
}

extern "C" void kernel_launch(void* const* d_in, const int* in_sizes, int n_in,
                              void* d_out, int out_size, void* d_ws, size_t ws_size,
                              hipStream_t stream) {
    const float* fm   = (const float*)d_in[0];
    const int*   rois = (const int*)d_in[1];
    float*       out  = (float*)d_out;

    const int N      = in_sizes[1] / 4;           // 1024 ROIs
    const int n_bins = N * POOLN * POOLN;         // 50176
    const int groups = (n_bins + BINS_PER_BLOCK - 1) / BINS_PER_BLOCK;  // 3136
    dim3 grid(groups * NXCD);                     // 25088 blocks
    roi_align_kernel<<<grid, 256, 0, stream>>>(fm, rois, out, n_bins);
}